// Round 3
// baseline (99.240 us; speedup 1.0000x reference)
//
#include <hip/hip_runtime.h>
#include <hip/hip_bf16.h>

// 2x2-patch softmax on a [B=16, C=64, H=256, W=256] fp32 tensor.
// Patch = rows (2h,2h+1) x cols (2w,2w+1). Softmax over the 4 values.
//
// Memory-bound streaming: 256 MiB read + 256 MiB write, each byte touched
// exactly once. Round 2 fix: nontemporal builtins need clang ext_vector_type,
// not HIP_vector_type (float4). Grid-stride at 2048 blocks.

#define W 256
#define N4_TOTAL (16 * 64 * 128 * 64)  // (B*C*H/2) rowpairs * (W/4) float4/row

typedef float v4f __attribute__((ext_vector_type(4)));

__global__ __launch_bounds__(256) void patch_softmax2x2(
    const float* __restrict__ x, float* __restrict__ y) {
    int stride = gridDim.x * blockDim.x;
    for (int i = blockIdx.x * blockDim.x + threadIdx.x; i < N4_TOTAL; i += stride) {
        int r = i >> 6;        // rowpair index: 64 float4 per 256-wide row
        int q = i & 63;        // which float4 within the row
        long base = (long)r * (2 * W) + q * 4;

        v4f t = __builtin_nontemporal_load(
            reinterpret_cast<const v4f*>(x + base));       // even row
        v4f b = __builtin_nontemporal_load(
            reinterpret_cast<const v4f*>(x + base + W));   // odd row

        // Patch A: {t.x, t.y, b.x, b.y}
        float mA = fmaxf(fmaxf(t.x, t.y), fmaxf(b.x, b.y));
        float eA0 = __expf(t.x - mA);
        float eA1 = __expf(t.y - mA);
        float eA2 = __expf(b.x - mA);
        float eA3 = __expf(b.y - mA);
        float invA = 1.0f / (eA0 + eA1 + eA2 + eA3);

        // Patch B: {t.z, t.w, b.z, b.w}
        float mB = fmaxf(fmaxf(t.z, t.w), fmaxf(b.z, b.w));
        float eB0 = __expf(t.z - mB);
        float eB1 = __expf(t.w - mB);
        float eB2 = __expf(b.z - mB);
        float eB3 = __expf(b.w - mB);
        float invB = 1.0f / (eB0 + eB1 + eB2 + eB3);

        v4f ot = {eA0 * invA, eA1 * invA, eB0 * invB, eB1 * invB};
        v4f ob = {eA2 * invA, eA3 * invA, eB2 * invB, eB3 * invB};

        __builtin_nontemporal_store(ot, reinterpret_cast<v4f*>(y + base));
        __builtin_nontemporal_store(ob, reinterpret_cast<v4f*>(y + base + W));
    }
}

extern "C" void kernel_launch(void* const* d_in, const int* in_sizes, int n_in,
                              void* d_out, int out_size, void* d_ws, size_t ws_size,
                              hipStream_t stream) {
    const float* x = (const float*)d_in[0];
    float* y = (float*)d_out;
    patch_softmax2x2<<<2048, 256, 0, stream>>>(x, y);
}

// Round 4
// 80.230 us; speedup vs baseline: 1.2369x; 1.2369x over previous
//
#include <hip/hip_runtime.h>
#include <hip/hip_bf16.h>

// 2x2-patch softmax on a [B=16, C=64, H=256, W=256] fp32 tensor.
// Patch = rows (2h,2h+1) x cols (2w,2w+1). Softmax over the 4 values.
//
// Memory-bound streaming: 256 MiB read + 256 MiB write.
// Round 4: ILP=2 (two independent float4-pairs per thread, all loads issued
// before compute), REGULAR loads (input ~fits 256MiB L3 across replays),
// nontemporal STORES only (write-once output, don't pollute L3).

#define W 256
#define N4_TOTAL (16 * 64 * 128 * 64)  // (B*C*H/2) rowpairs * (W/4) float4/row
#define HALF (N4_TOTAL / 2)

typedef float v4f __attribute__((ext_vector_type(4)));

__device__ __forceinline__ void softmax_pair(v4f t, v4f b, v4f& ot, v4f& ob) {
    // Patch A: {t.x, t.y, b.x, b.y}
    float mA = fmaxf(fmaxf(t.x, t.y), fmaxf(b.x, b.y));
    float eA0 = __expf(t.x - mA);
    float eA1 = __expf(t.y - mA);
    float eA2 = __expf(b.x - mA);
    float eA3 = __expf(b.y - mA);
    float invA = 1.0f / (eA0 + eA1 + eA2 + eA3);
    // Patch B: {t.z, t.w, b.z, b.w}
    float mB = fmaxf(fmaxf(t.z, t.w), fmaxf(b.z, b.w));
    float eB0 = __expf(t.z - mB);
    float eB1 = __expf(t.w - mB);
    float eB2 = __expf(b.z - mB);
    float eB3 = __expf(b.w - mB);
    float invB = 1.0f / (eB0 + eB1 + eB2 + eB3);
    ot = (v4f){eA0 * invA, eA1 * invA, eB0 * invB, eB1 * invB};
    ob = (v4f){eA2 * invA, eA3 * invA, eB2 * invB, eB3 * invB};
}

__global__ __launch_bounds__(256) void patch_softmax2x2(
    const float* __restrict__ x, float* __restrict__ y) {
    int i = blockIdx.x * blockDim.x + threadIdx.x;  // [0, HALF)

    int r0 = i >> 6;
    int q0 = i & 63;
    long base0 = (long)r0 * (2 * W) + q0 * 4;

    int j = i + HALF;
    int r1 = j >> 6;
    int q1 = j & 63;
    long base1 = (long)r1 * (2 * W) + q1 * 4;

    // Issue all 4 loads before any compute (MLP).
    v4f t0 = *reinterpret_cast<const v4f*>(x + base0);
    v4f b0 = *reinterpret_cast<const v4f*>(x + base0 + W);
    v4f t1 = *reinterpret_cast<const v4f*>(x + base1);
    v4f b1 = *reinterpret_cast<const v4f*>(x + base1 + W);

    v4f ot0, ob0, ot1, ob1;
    softmax_pair(t0, b0, ot0, ob0);
    softmax_pair(t1, b1, ot1, ob1);

    __builtin_nontemporal_store(ot0, reinterpret_cast<v4f*>(y + base0));
    __builtin_nontemporal_store(ob0, reinterpret_cast<v4f*>(y + base0 + W));
    __builtin_nontemporal_store(ot1, reinterpret_cast<v4f*>(y + base1));
    __builtin_nontemporal_store(ob1, reinterpret_cast<v4f*>(y + base1 + W));
}

extern "C" void kernel_launch(void* const* d_in, const int* in_sizes, int n_in,
                              void* d_out, int out_size, void* d_ws, size_t ws_size,
                              hipStream_t stream) {
    const float* x = (const float*)d_in[0];
    float* y = (float*)d_out;
    patch_softmax2x2<<<HALF / 256, 256, 0, stream>>>(x, y);  // 16384 blocks
}